// Round 13
// baseline (552.527 us; speedup 1.0000x reference)
//
#include <hip/hip_runtime.h>

#define KNB 16
#define BSZ 8
#define NPT 2048

typedef __attribute__((ext_vector_type(8))) short bf16x8;
typedef __attribute__((ext_vector_type(4))) float f32x4;

__device__ __forceinline__ float lrelu(float x) { return x >= 0.f ? x : 0.01f * x; }

__device__ __forceinline__ unsigned short bf16rne(float f) {
    union { float f; unsigned int u; } v; v.f = f;
    return (unsigned short)((v.u + 0x7FFFu + ((v.u >> 16) & 1u)) >> 16);
}

// pack candidate index into low 11 mantissa bits of fp32 score -> unique,
// float-comparable key. idx = bits & 2047.
__device__ __forceinline__ float packkey(float d, int idx) {
    union { float f; unsigned int u; } v; v.f = d;
    v.u = (v.u & 0xFFFFF800u) | (unsigned int)idx;
    return v.f;
}

__device__ __forceinline__ float max16(const float* L) {
    float m = L[0];
#pragma unroll
    for (int u = 1; u < 16; ++u) m = fmaxf(m, L[u]);
    return m;
}

// ---------------------------------------------------------------------------
// Weight prep: w[K][N] fp32 -> wt[N][K] bf16 (B-operand layout, block2/3)
// ---------------------------------------------------------------------------
__global__ void wprep_kernel(const float* __restrict__ w, unsigned short* __restrict__ wt,
                             int K, int N) {
    int i = blockIdx.x * 256 + threadIdx.x;
    if (i < K * N) { int k = i / N, n = i - k * N; wt[n * K + k] = bf16rne(w[i]); }
}

// ---------------------------------------------------------------------------
// Block1 weight prep: A-operand layout [out][Kpad] bf16, K zero-padded.
// ---------------------------------------------------------------------------
__global__ void wprep_b1_kernel(const float* __restrict__ w1, const float* __restrict__ w2,
                                const float* __restrict__ w3,
                                unsigned short* __restrict__ w1a, unsigned short* __restrict__ w2a,
                                unsigned short* __restrict__ w3a) {
    int i = blockIdx.x * 256 + threadIdx.x;
    if (i < 512) {
        int n = i >> 5, k = i & 31;
        w1a[i] = (k < 6) ? bf16rne(w1[k * 16 + n]) : (unsigned short)0;
    } else if (i < 2560) {
        int j = i - 512, n = j >> 5, k = j & 31;
        w2a[j] = (k < 16) ? bf16rne(w2[k * 64 + n]) : (unsigned short)0;
    } else if (i < 4608) {
        int j = i - 2560, n = j >> 6, k = j & 63;
        w3a[j] = bf16rne(w3[k * 32 + n]);
    }
}

// ---------------------------------------------------------------------------
// Per-point squared norms
// ---------------------------------------------------------------------------
template<int C>
__global__ void norms16_kernel(const unsigned short* __restrict__ feat, float* __restrict__ out) {
    int gid = blockIdx.x * blockDim.x + threadIdx.x;
    if (gid < BSZ * NPT) {
        const unsigned short* p = feat + (size_t)gid * C;
        float s = 0.f;
#pragma unroll
        for (int c = 0; c < C; ++c) {
            union { unsigned int u; float f; } v; v.u = ((unsigned int)p[c]) << 16;
            s = fmaf(v.f, v.f, s);
        }
        out[gid] = s;
    }
}

template<int C>
__global__ void norms_kernel(const float* __restrict__ feat, float* __restrict__ out) {
    int gid = blockIdx.x * blockDim.x + threadIdx.x;
    if (gid < BSZ * NPT) {
        const float* p = feat + (size_t)gid * C;
        float s = 0.f;
#pragma unroll
        for (int c = 0; c < C; ++c) s = fmaf(p[c], p[c], s);
        out[gid] = s;
    }
}

// ---------------------------------------------------------------------------
// KNN C=3, fp32, j-split JS, dual top-16 lists (even/odd candidates).
// Lane = query; wave scans a quarter of the js range; cross-wave merge at
// end (2 barriers). JS=8 halves per-lane candidate stream (R13).
// ---------------------------------------------------------------------------
template<int JS>
__launch_bounds__(256, 3)
__global__ void knn3_kernel(const float* __restrict__ feat,
                            const float* __restrict__ norms,
                            float* __restrict__ cand) {
    constexpr int JL = NPT / JS;
    constexpr int JP = JL / 4;
    const int b = blockIdx.z, js = blockIdx.y, i0 = blockIdx.x * 64;
    const int t = threadIdx.x, w = t >> 6, lane = t & 63;
    const float* fb = feat + (size_t)b * NPT * 3;
    const float* nb = norms + (size_t)b * NPT;

    __shared__ float sS[4][64][17];

    float q0, q1, q2;
    { const float* qp = fb + (size_t)(i0 + lane) * 3; q0 = qp[0]; q1 = qp[1]; q2 = qp[2]; }

    float LA[16], LB[16];
#pragma unroll
    for (int u = 0; u < 16; ++u) { LA[u] = packkey(3e38f, u); LB[u] = packkey(3e38f, u); }
    float mxA = max16(LA), mxB = max16(LB);

    auto insA = [&](float k) {
        if (k < mxA) {
#pragma unroll
            for (int u = 0; u < 16; ++u) LA[u] = (LA[u] == mxA) ? k : LA[u];
            mxA = max16(LA);
        }
    };
    auto insB = [&](float k) {
        if (k < mxB) {
#pragma unroll
            for (int u = 0; u < 16; ++u) LB[u] = (LB[u] == mxB) ? k : LB[u];
            mxB = max16(LB);
        }
    };

    const int jbeg = js * JL + w * JP;
#pragma unroll 2
    for (int jj = 0; jj < JP; jj += 2) {
        const int j = jbeg + jj;
        const float* pp = fb + (size_t)j * 3;
        const float dA = fmaf(-2.f, fmaf(q0, pp[0], fmaf(q1, pp[1], q2 * pp[2])), nb[j]);
        const float dB = fmaf(-2.f, fmaf(q0, pp[3], fmaf(q1, pp[4], q2 * pp[5])), nb[j + 1]);
        insA(packkey(dA, j));
        insB(packkey(dB, j + 1));
    }
    // merge B into A
#pragma unroll
    for (int c = 0; c < 16; ++c) insA(LB[c]);

    // cross-wave merge (rows = lanes)
#pragma unroll
    for (int c = 0; c < 16; ++c) sS[w][lane][c] = LA[c];
    __syncthreads();
    if (w == 0 || w == 2) {
#pragma unroll
        for (int c = 0; c < 16; ++c) insA(sS[w + 1][lane][c]);
        if (w == 2) {
#pragma unroll
            for (int c = 0; c < 16; ++c) sS[2][lane][c] = LA[c];
        }
    }
    __syncthreads();
    if (w == 0) {
#pragma unroll
        for (int c = 0; c < 16; ++c) insA(sS[2][lane][c]);
        float* o = cand + (((size_t)b * NPT + i0 + lane) * JS + js) * 16;
#pragma unroll
        for (int c = 0; c < 16; ++c) o[c] = LA[c];
    }
}

// ---------------------------------------------------------------------------
// KNN via bf16 MFMA — exact R10 structure (single top-16 list; proven
// 64 us @ JS=4), now at JS=8 to halve the per-lane candidate stream.
// A = 64 query rows stationary in registers; wave w streams its own 16
// candidates per 64-tile; scores via wave-private LDS strip (no barrier);
// cross-wave merge at end (2 barriers total).
// ---------------------------------------------------------------------------
template<int C, int JS>
__launch_bounds__(256, 3)
__global__ void knn_mfma_kernel(const unsigned short* __restrict__ fb16,
                                const float* __restrict__ norms,
                                float* __restrict__ cand) {
    constexpr int JL = NPT / JS;
    constexpr int KS = C / 32;
    const int b    = blockIdx.z;
    const int js   = blockIdx.y;
    const int i0   = blockIdx.x * 64;
    const int t    = threadIdx.x;
    const int w    = t >> 6;
    const int lane = t & 63;
    const int l15  = lane & 15;
    const int quad = lane >> 4;
    const unsigned short* fbb = fb16 + (size_t)b * NPT * C;
    const float* nb = norms + (size_t)b * NPT;

    __shared__ float sS[4][64][17];

    bf16x8 afr[KS * 4];
#pragma unroll
    for (int ks = 0; ks < KS; ++ks)
#pragma unroll
        for (int mi = 0; mi < 4; ++mi)
            afr[ks * 4 + mi] = *(const bf16x8*)(fbb + (size_t)(i0 + mi * 16 + l15) * C + ks * 32 + quad * 8);

    float L[16];
#pragma unroll
    for (int u = 0; u < 16; ++u) L[u] = 3e38f;
    float mx = 3e38f;

    auto ins = [&](float k) {
        if (k < mx) {
#pragma unroll
            for (int u = 0; u < 16; ++u) L[u] = (L[u] == mx) ? k : L[u];
            mx = max16(L);
        }
    };

    const int jbeg = js * JL;
#pragma unroll 1
    for (int j0 = jbeg; j0 < jbeg + JL; j0 += 64) {
        f32x4 acc[4];
#pragma unroll
        for (int mi = 0; mi < 4; ++mi) acc[mi] = (f32x4){0.f, 0.f, 0.f, 0.f};
        const unsigned short* prow = fbb + (size_t)(j0 + w * 16 + l15) * C + quad * 8;
#pragma unroll
        for (int ks = 0; ks < KS; ++ks) {
            const bf16x8 bfr = *(const bf16x8*)(prow + ks * 32);
#pragma unroll
            for (int mi = 0; mi < 4; ++mi)
                acc[mi] = __builtin_amdgcn_mfma_f32_16x16x32_bf16(afr[ks * 4 + mi], bfr, acc[mi], 0, 0, 0);
        }
        const float nv  = nb[j0 + w * 16 + l15];
        const int  cidx = j0 + w * 16 + l15;
        // D layout: col(candidate)=l15, row(query)=mi*16+quad*4+r. Write
        // packed keys to this wave's private strip; read back transposed.
#pragma unroll
        for (int mi = 0; mi < 4; ++mi)
#pragma unroll
            for (int r = 0; r < 4; ++r)
                sS[w][mi * 16 + quad * 4 + r][l15] = packkey(fmaf(-2.f, acc[mi][r], nv), cidx);
        float k0[16];
#pragma unroll
        for (int c = 0; c < 16; ++c) k0[c] = sS[w][lane][c];
        if (j0 == jbeg) {
#pragma unroll
            for (int c = 0; c < 16; ++c) L[c] = k0[c];
            mx = max16(L);
        } else {
#pragma unroll
            for (int c = 0; c < 16; ++c) ins(k0[c]);
        }
    }

    // cross-wave merge: per query row, 4 column-partition lists -> 16
#pragma unroll
    for (int c = 0; c < 16; ++c) sS[w][lane][c] = L[c];
    __syncthreads();
    if (w == 0 || w == 2) {
#pragma unroll
        for (int c = 0; c < 16; ++c) ins(sS[w + 1][lane][c]);
        if (w == 2) {
#pragma unroll
            for (int c = 0; c < 16; ++c) sS[2][lane][c] = L[c];
        }
    }
    __syncthreads();
    if (w == 0) {
#pragma unroll
        for (int c = 0; c < 16; ++c) ins(sS[2][lane][c]);
        float* o = cand + (((size_t)b * NPT + i0 + lane) * JS + js) * 16;
#pragma unroll
        for (int c = 0; c < 16; ++c) o[c] = L[c];
    }
}

// ---------------------------------------------------------------------------
// Merge JS packed-key lists per query -> final top-16 indices.
// ---------------------------------------------------------------------------
template<int JS>
__launch_bounds__(256)
__global__ void knn_merge_kernel(const float* __restrict__ cand, int* __restrict__ knn_out) {
    const int q = blockIdx.x * 256 + threadIdx.x;
    const float* pd = cand + (size_t)q * JS * 16;
    float L[16];
#pragma unroll
    for (int u = 0; u < 16; ++u) L[u] = pd[u];
    float mx = max16(L);
#pragma unroll 2
    for (int u = 16; u < JS * 16; ++u) {
        const float k = pd[u];
        if (k < mx) {
#pragma unroll
            for (int v = 0; v < 16; ++v) L[v] = (L[v] == mx) ? k : L[v];
            mx = max16(L);
        }
    }
    int* o = knn_out + (size_t)q * KNB;
#pragma unroll
    for (int u = 0; u < 16; ++u) {
        union { float f; unsigned int v; } z; z.f = L[u];
        o[u] = (int)(z.v & 2047u);
    }
}

// ---------------------------------------------------------------------------
// Block 1 via MFMA, swapped operands (R10, unchanged). Writes x2 in bf16.
// ---------------------------------------------------------------------------
__launch_bounds__(256, 3)
__global__ void block1_mfma_kernel(const float* __restrict__ x, const int* __restrict__ knn,
                                   const unsigned short* __restrict__ w1a, const float* __restrict__ b1,
                                   const unsigned short* __restrict__ w2a, const float* __restrict__ b2,
                                   const unsigned short* __restrict__ w3a, const float* __restrict__ b3,
                                   unsigned short* __restrict__ x2b) {
    const int w = threadIdx.x >> 6, lane = threadIdx.x & 63;
    const int l15 = lane & 15, quad = lane >> 4;

    const bf16x8 W1 = *(const bf16x8*)(w1a + l15 * 32 + quad * 8);
    bf16x8 W2[4];
#pragma unroll
    for (int nt = 0; nt < 4; ++nt)
        W2[nt] = *(const bf16x8*)(w2a + (nt * 16 + l15) * 32 + quad * 8);
    bf16x8 W3[2][2];
#pragma unroll
    for (int tt = 0; tt < 2; ++tt)
#pragma unroll
        for (int ks = 0; ks < 2; ++ks)
            W3[tt][ks] = *(const bf16x8*)(w3a + (tt * 16 + l15) * 64 + ks * 32 + quad * 8);
    float b1v[4], b2v[4][4], b3v[2][4];
#pragma unroll
    for (int r = 0; r < 4; ++r) b1v[r] = b1[quad * 4 + r];
#pragma unroll
    for (int nt = 0; nt < 4; ++nt)
#pragma unroll
        for (int r = 0; r < 4; ++r) b2v[nt][r] = b2[nt * 16 + quad * 4 + r];
#pragma unroll
    for (int tt = 0; tt < 2; ++tt)
#pragma unroll
        for (int r = 0; r < 4; ++r) b3v[tt][r] = b3[tt * 16 + quad * 4 + r];

    const int src0 = ((2 * quad) & 3) * 16 + l15;
    const int src1 = ((2 * quad + 1) & 3) * 16 + l15;
    const int ntsel = quad >> 1;

    const int p0 = blockIdx.x * 16 + w * 4;
#pragma unroll 1
    for (int pi = 0; pi < 4; ++pi) {
        const int p = p0 + pi, b = p >> 11, n = p & (NPT - 1);
        int d0 = 0, d1 = 0, d2 = 0;
        if (quad == 0) {
            const float* xc = x + ((size_t)b * NPT + n) * 3;
            const int jn = knn[(size_t)p * KNB + l15];
            const float* xn = x + ((size_t)b * NPT + jn) * 3;
            const unsigned s0 = bf16rne(xc[0]), s1 = bf16rne(xc[1]), s2 = bf16rne(xc[2]);
            const unsigned s3 = bf16rne(xn[0]), s4 = bf16rne(xn[1]), s5 = bf16rne(xn[2]);
            d0 = (int)(s0 | (s1 << 16));
            d1 = (int)(s2 | (s3 << 16));
            d2 = (int)(s4 | (s5 << 16));
        }
        union { int i[4]; bf16x8 v; } B1;
        B1.i[0] = d0; B1.i[1] = d1; B1.i[2] = d2; B1.i[3] = 0;
        const f32x4 a1 = __builtin_amdgcn_mfma_f32_16x16x32_bf16(W1, B1.v, (f32x4){0.f, 0.f, 0.f, 0.f}, 0, 0, 0);

        int h10, h11;
        {
            const unsigned t0 = bf16rne(lrelu(a1[0] + b1v[0]));
            const unsigned t1 = bf16rne(lrelu(a1[1] + b1v[1]));
            const unsigned t2 = bf16rne(lrelu(a1[2] + b1v[2]));
            const unsigned t3 = bf16rne(lrelu(a1[3] + b1v[3]));
            h10 = (int)(t0 | (t1 << 16));
            h11 = (int)(t2 | (t3 << 16));
        }
        union { int i[4]; bf16x8 v; } B2;
        {
            const int e0 = __shfl(h10, src0), e1 = __shfl(h11, src0);
            const int e2 = __shfl(h10, src1), e3 = __shfl(h11, src1);
            const bool val = quad < 2;
            B2.i[0] = val ? e0 : 0; B2.i[1] = val ? e1 : 0;
            B2.i[2] = val ? e2 : 0; B2.i[3] = val ? e3 : 0;
        }
        f32x4 a2[4];
#pragma unroll
        for (int nt = 0; nt < 4; ++nt)
            a2[nt] = __builtin_amdgcn_mfma_f32_16x16x32_bf16(W2[nt], B2.v, (f32x4){0.f, 0.f, 0.f, 0.f}, 0, 0, 0);
        int dpk[4][2];
#pragma unroll
        for (int nt = 0; nt < 4; ++nt) {
            const unsigned t0 = bf16rne(lrelu(a2[nt][0] + b2v[nt][0]));
            const unsigned t1 = bf16rne(lrelu(a2[nt][1] + b2v[nt][1]));
            const unsigned t2 = bf16rne(lrelu(a2[nt][2] + b2v[nt][2]));
            const unsigned t3 = bf16rne(lrelu(a2[nt][3] + b2v[nt][3]));
            dpk[nt][0] = (int)(t0 | (t1 << 16));
            dpk[nt][1] = (int)(t2 | (t3 << 16));
        }
        f32x4 a3[2] = { (f32x4){0.f, 0.f, 0.f, 0.f}, (f32x4){0.f, 0.f, 0.f, 0.f} };
#pragma unroll
        for (int ks = 0; ks < 2; ++ks) {
            union { int i[4]; bf16x8 v; } B3;
            const int a0l = __shfl(dpk[2 * ks][0], src0), a0h = __shfl(dpk[2 * ks + 1][0], src0);
            const int a1l = __shfl(dpk[2 * ks][1], src0), a1h = __shfl(dpk[2 * ks + 1][1], src0);
            const int a2l = __shfl(dpk[2 * ks][0], src1), a2h = __shfl(dpk[2 * ks + 1][0], src1);
            const int a3l = __shfl(dpk[2 * ks][1], src1), a3h = __shfl(dpk[2 * ks + 1][1], src1);
            B3.i[0] = ntsel ? a0h : a0l;
            B3.i[1] = ntsel ? a1h : a1l;
            B3.i[2] = ntsel ? a2h : a2l;
            B3.i[3] = ntsel ? a3h : a3l;
#pragma unroll
            for (int tt = 0; tt < 2; ++tt)
                a3[tt] = __builtin_amdgcn_mfma_f32_16x16x32_bf16(W3[tt][ks], B3.v, a3[tt], 0, 0, 0);
        }
#pragma unroll
        for (int tt = 0; tt < 2; ++tt) {
#pragma unroll
            for (int r = 0; r < 4; ++r) {
                float s = lrelu(a3[tt][r] + b3v[tt][r]);
                s += __shfl_xor(s, 1);
                s += __shfl_xor(s, 2);
                s += __shfl_xor(s, 4);
                s += __shfl_xor(s, 8);
                if (l15 == 0)
                    x2b[(size_t)p * 32 + tt * 16 + quad * 4 + r] = bf16rne(s);
            }
        }
    }
}

// ---------------------------------------------------------------------------
// Block 2 fused, weight-stationary (R9/R10, unchanged). x3 out bf16.
// ---------------------------------------------------------------------------
__launch_bounds__(256, 2)
__global__ void block2_fused_kernel(const unsigned short* __restrict__ x2b,
                                    const int* __restrict__ knn,
                                    const unsigned short* __restrict__ w1t,  // [256][64]
                                    const float* __restrict__ b1,
                                    const unsigned short* __restrict__ w2t,  // [128][256]
                                    const float* __restrict__ b2,
                                    unsigned short* __restrict__ x3b) {
    const int w    = threadIdx.x >> 6;
    const int lane = threadIdx.x & 63;
    const int l15  = lane & 15, quad = lane >> 4;
    __shared__ __align__(16) unsigned short sH1[2][16][264];

    bf16x8 B1[4][2];
#pragma unroll
    for (int nt2 = 0; nt2 < 4; ++nt2)
#pragma unroll
        for (int ks = 0; ks < 2; ++ks)
            B1[nt2][ks] = *(const bf16x8*)(w1t + (size_t)(w * 64 + nt2 * 16 + l15) * 64 + ks * 32 + quad * 8);
    bf16x8 B2[2][8];
#pragma unroll
    for (int nt2 = 0; nt2 < 2; ++nt2)
#pragma unroll
        for (int ks = 0; ks < 8; ++ks)
            B2[nt2][ks] = *(const bf16x8*)(w2t + (size_t)(w * 32 + nt2 * 16 + l15) * 256 + ks * 32 + quad * 8);
    float b1v[4];
#pragma unroll
    for (int nt2 = 0; nt2 < 4; ++nt2) b1v[nt2] = b1[w * 64 + nt2 * 16 + l15];
    float b2v[2];
#pragma unroll
    for (int nt2 = 0; nt2 < 2; ++nt2) b2v[nt2] = b2[w * 32 + nt2 * 16 + l15];

    const int p0 = blockIdx.x * 8;
#pragma unroll 1
    for (int pi = 0; pi < 8; ++pi) {
        const int p = p0 + pi, b = p >> 11, buf = pi & 1;
        const int nbr = knn[(size_t)p * KNB + l15];
        const bf16x8 a0 = *(const bf16x8*)(x2b + (size_t)p * 32 + quad * 8);
        const bf16x8 a1 = *(const bf16x8*)(x2b + ((size_t)(b * NPT) + nbr) * 32 + quad * 8);
#pragma unroll
        for (int nt2 = 0; nt2 < 4; ++nt2) {
            f32x4 acc = (f32x4){0.f, 0.f, 0.f, 0.f};
            acc = __builtin_amdgcn_mfma_f32_16x16x32_bf16(a0, B1[nt2][0], acc, 0, 0, 0);
            acc = __builtin_amdgcn_mfma_f32_16x16x32_bf16(a1, B1[nt2][1], acc, 0, 0, 0);
#pragma unroll
            for (int r = 0; r < 4; ++r)
                sH1[buf][quad * 4 + r][w * 64 + nt2 * 16 + l15] = bf16rne(lrelu(acc[r] + b1v[nt2]));
        }
        __syncthreads();
        bf16x8 af[8];
#pragma unroll
        for (int ks = 0; ks < 8; ++ks)
            af[ks] = *(const bf16x8*)&sH1[buf][l15][ks * 32 + quad * 8];
#pragma unroll
        for (int nt2 = 0; nt2 < 2; ++nt2) {
            f32x4 acc = (f32x4){0.f, 0.f, 0.f, 0.f};
#pragma unroll
            for (int ks = 0; ks < 8; ++ks)
                acc = __builtin_amdgcn_mfma_f32_16x16x32_bf16(af[ks], B2[nt2][ks], acc, 0, 0, 0);
            float s = 0.f;
#pragma unroll
            for (int r = 0; r < 4; ++r) s += lrelu(acc[r] + b2v[nt2]);
            s += __shfl_xor(s, 16);
            s += __shfl_xor(s, 32);
            if (quad == 0) x3b[(size_t)p * 128 + w * 32 + nt2 * 16 + l15] = bf16rne(s);
        }
    }
}

// ---------------------------------------------------------------------------
// Block 3 fused, weight-stationary (R9, unchanged): x4 fp32 out.
// ---------------------------------------------------------------------------
__launch_bounds__(256, 3)
__global__ void block3_fused_kernel(const unsigned short* __restrict__ x3b,
                                    const int* __restrict__ knn,
                                    const unsigned short* __restrict__ w3t,  // [128][256]
                                    const float* __restrict__ bias,
                                    float* __restrict__ x4) {
    const int w    = threadIdx.x >> 6;
    const int lane = threadIdx.x & 63;
    const int l15  = lane & 15, quad = lane >> 4;

    bf16x8 B3[2][8];
#pragma unroll
    for (int nt2 = 0; nt2 < 2; ++nt2)
#pragma unroll
        for (int ks = 0; ks < 8; ++ks)
            B3[nt2][ks] = *(const bf16x8*)(w3t + (size_t)(w * 32 + nt2 * 16 + l15) * 256 + ks * 32 + quad * 8);
    float bv[2];
#pragma unroll
    for (int nt2 = 0; nt2 < 2; ++nt2) bv[nt2] = bias[w * 32 + nt2 * 16 + l15];

    const int p0 = blockIdx.x * 8;
#pragma unroll 1
    for (int pi = 0; pi < 8; ++pi) {
        const int p = p0 + pi, b = p >> 11;
        const int nbr = knn[(size_t)p * KNB + l15];
        const unsigned short* ctr = x3b + (size_t)p * 128 + quad * 8;
        const unsigned short* nbp = x3b + ((size_t)(b * NPT) + nbr) * 128 + quad * 8;
        bf16x8 af[8];
#pragma unroll
        for (int ks = 0; ks < 4; ++ks) af[ks] = *(const bf16x8*)(ctr + ks * 32);
#pragma unroll
        for (int ks = 0; ks < 4; ++ks) af[4 + ks] = *(const bf16x8*)(nbp + ks * 32);
#pragma unroll
        for (int nt2 = 0; nt2 < 2; ++nt2) {
            f32x4 acc = (f32x4){0.f, 0.f, 0.f, 0.f};
#pragma unroll
            for (int ks = 0; ks < 8; ++ks)
                acc = __builtin_amdgcn_mfma_f32_16x16x32_bf16(af[ks], B3[nt2][ks], acc, 0, 0, 0);
            float s = 0.f;
#pragma unroll
            for (int r = 0; r < 4; ++r) s += lrelu(acc[r] + bv[nt2]);
            s += __shfl_xor(s, 16);
            s += __shfl_xor(s, 32);
            if (quad == 0) x4[(size_t)p * 128 + w * 32 + nt2 * 16 + l15] = s;
        }
    }
}

// ---------------------------------------------------------------------------
// Maxpool stage 1
// ---------------------------------------------------------------------------
__launch_bounds__(128)
__global__ void maxpool_partial_kernel(const float* __restrict__ x4,
                                       float* __restrict__ part) {
    const int chunk = blockIdx.x, b = blockIdx.y, t = threadIdx.x;
    const float* xb = x4 + ((size_t)b * NPT + (size_t)chunk * 128) * 128;
    float m = -1e30f;
#pragma unroll 8
    for (int n = 0; n < 128; ++n) m = fmaxf(m, xb[(size_t)n * 128 + t]);
    part[((size_t)b * 16 + chunk) * 128 + t] = m;
}

// ---------------------------------------------------------------------------
// Head stage 2
// ---------------------------------------------------------------------------
__launch_bounds__(128)
__global__ void head2_kernel(const float* __restrict__ part,
                             const float* __restrict__ fc1w, const float* __restrict__ fc1b,
                             const float* __restrict__ fc2w, const float* __restrict__ fc2b,
                             const float* __restrict__ fc3w, const float* __restrict__ fc3b,
                             float* __restrict__ out) {
    const int g = blockIdx.x, b = blockIdx.y, t = threadIdx.x;
    __shared__ float s5[128], s6[128], s7[128];
    float m = -1e30f;
#pragma unroll
    for (int c = 0; c < 16; ++c)
        m = fmaxf(m, part[((size_t)b * 16 + c) * 128 + t]);
    s5[t] = m;
    __syncthreads();
    float a = fc1b[t];
#pragma unroll 4
    for (int i = 0; i < 128; ++i) a = fmaf(s5[i], fc1w[i * 128 + t], a);
    s6[t] = lrelu(a);
    __syncthreads();
    a = fc2b[t];
#pragma unroll 4
    for (int i = 0; i < 128; ++i) a = fmaf(s6[i], fc2w[i * 128 + t], a);
    s7[t] = lrelu(a);
    __syncthreads();
    const int o = g * 128 + t;
    float acc = fc3b[o];
#pragma unroll 4
    for (int i = 0; i < 128; ++i) acc = fmaf(s7[i], fc3w[(size_t)i * 6144 + o], acc);
    out[(size_t)b * 6144 + o] = acc;
}

// ---------------------------------------------------------------------------
extern "C" void kernel_launch(void* const* d_in, const int* in_sizes, int n_in,
                              void* d_out, int out_size, void* d_ws, size_t ws_size,
                              hipStream_t stream) {
    const float* x    = (const float*)d_in[0];
    const float* h1w1 = (const float*)d_in[1];
    const float* h1b1 = (const float*)d_in[2];
    const float* h1w2 = (const float*)d_in[3];
    const float* h1b2 = (const float*)d_in[4];
    const float* h1w3 = (const float*)d_in[5];
    const float* h1b3 = (const float*)d_in[6];
    const float* h2w1 = (const float*)d_in[7];
    const float* h2b1 = (const float*)d_in[8];
    const float* h2w2 = (const float*)d_in[9];
    const float* h2b2 = (const float*)d_in[10];
    const float* h3w1 = (const float*)d_in[11];
    const float* h3b1 = (const float*)d_in[12];
    const float* fc1w = (const float*)d_in[13];
    const float* fc1b = (const float*)d_in[14];
    const float* fc2w = (const float*)d_in[15];
    const float* fc2b = (const float*)d_in[16];
    const float* fc3w = (const float*)d_in[17];
    const float* fc3b = (const float*)d_in[18];

    float* ws = (float*)d_ws;
    unsigned short* x2b16 = (unsigned short*)ws;              //  524288 sh (262144 fl)
    unsigned short* x3b16 = (unsigned short*)(ws + 262144);   // 2097152 sh (1048576 fl)
    float* x4   = ws + 1310720;                               // 2097152 fl
    int*   idx  = (int*)(ws + 3407872);                       //  262144 int
    float* nrm  = ws + 3670016;                               //   16384 fl
    float* part = ws + 3686400;                               //   16384 fl
    unsigned short* w1t = (unsigned short*)(ws + 3702784);    //  16384 sh
    unsigned short* w2t = (unsigned short*)(ws + 3710976);    //  32768 sh
    unsigned short* w3t = (unsigned short*)(ws + 3727360);    //  32768 sh
    unsigned short* w1a = (unsigned short*)(ws + 3743744);    //    512 sh
    unsigned short* w2a = (unsigned short*)(ws + 3744000);    //   2048 sh
    unsigned short* w3a = (unsigned short*)(ws + 3745024);    //   2048 sh
    // JS=8 packed-key candidate buffer (2M floats = 8 MB) ALIASES x4: the
    // last knn_merge consumes cand before block3 writes x4 (single stream).
    float* cd   = x4;
    float* out  = (float*)d_out;

    const dim3 kg(32, 8, 8);   // (qtile, j-split=8, batch)

    wprep_kernel<<<64, 256, 0, stream>>>(h2w1, w1t, 64, 256);
    wprep_kernel<<<128, 256, 0, stream>>>(h2w2, w2t, 256, 128);
    wprep_kernel<<<128, 256, 0, stream>>>(h3w1, w3t, 256, 128);
    wprep_b1_kernel<<<18, 256, 0, stream>>>(h1w1, h1w2, h1w3, w1a, w2a, w3a);

    norms_kernel<3><<<64, 256, 0, stream>>>(x, nrm);
    knn3_kernel<8><<<kg, 256, 0, stream>>>(x, nrm, cd);
    knn_merge_kernel<8><<<64, 256, 0, stream>>>(cd, idx);
    block1_mfma_kernel<<<1024, 256, 0, stream>>>(x, idx, w1a, h1b1, w2a, h1b2, w3a, h1b3, x2b16);

    norms16_kernel<32><<<64, 256, 0, stream>>>(x2b16, nrm);
    knn_mfma_kernel<32, 8><<<kg, 256, 0, stream>>>(x2b16, nrm, cd);
    knn_merge_kernel<8><<<64, 256, 0, stream>>>(cd, idx);
    block2_fused_kernel<<<BSZ * NPT / 8, 256, 0, stream>>>(x2b16, idx, w1t, h2b1, w2t, h2b2, x3b16);

    norms16_kernel<128><<<64, 256, 0, stream>>>(x3b16, nrm);
    knn_mfma_kernel<128, 8><<<kg, 256, 0, stream>>>(x3b16, nrm, cd);
    knn_merge_kernel<8><<<64, 256, 0, stream>>>(cd, idx);
    block3_fused_kernel<<<BSZ * NPT / 8, 256, 0, stream>>>(x3b16, idx, w3t, h3b1, x4);

    maxpool_partial_kernel<<<dim3(16, 8), 128, 0, stream>>>(x4, part);
    head2_kernel<<<dim3(48, 8), 128, 0, stream>>>(part, fc1w, fc1b, fc2w, fc2b,
                                                  fc3w, fc3b, out);
}

// Round 14
// 494.747 us; speedup vs baseline: 1.1168x; 1.1168x over previous
//
#include <hip/hip_runtime.h>

#define KNB 16
#define BSZ 8
#define NPT 2048

typedef __attribute__((ext_vector_type(8))) short bf16x8;
typedef __attribute__((ext_vector_type(4))) float f32x4;

__device__ __forceinline__ float lrelu(float x) { return x >= 0.f ? x : 0.01f * x; }

__device__ __forceinline__ unsigned short bf16rne(float f) {
    union { float f; unsigned int u; } v; v.f = f;
    return (unsigned short)((v.u + 0x7FFFu + ((v.u >> 16) & 1u)) >> 16);
}

// pack candidate index into low 11 mantissa bits of fp32 score -> unique,
// float-comparable key. idx = bits & 2047.
__device__ __forceinline__ float packkey(float d, int idx) {
    union { float f; unsigned int u; } v; v.f = d;
    v.u = (v.u & 0xFFFFF800u) | (unsigned int)idx;
    return v.f;
}

__device__ __forceinline__ float max16(const float* L) {
    float m = L[0];
#pragma unroll
    for (int u = 1; u < 16; ++u) m = fmaxf(m, L[u]);
    return m;
}

// ---------------------------------------------------------------------------
// Weight prep: w[K][N] fp32 -> wt[N][K] bf16 (B-operand layout, block2/3)
// ---------------------------------------------------------------------------
__global__ void wprep_kernel(const float* __restrict__ w, unsigned short* __restrict__ wt,
                             int K, int N) {
    int i = blockIdx.x * 256 + threadIdx.x;
    if (i < K * N) { int k = i / N, n = i - k * N; wt[n * K + k] = bf16rne(w[i]); }
}

// ---------------------------------------------------------------------------
// Block1 weight prep: A-operand layout [out][Kpad] bf16, K zero-padded.
// ---------------------------------------------------------------------------
__global__ void wprep_b1_kernel(const float* __restrict__ w1, const float* __restrict__ w2,
                                const float* __restrict__ w3,
                                unsigned short* __restrict__ w1a, unsigned short* __restrict__ w2a,
                                unsigned short* __restrict__ w3a) {
    int i = blockIdx.x * 256 + threadIdx.x;
    if (i < 512) {
        int n = i >> 5, k = i & 31;
        w1a[i] = (k < 6) ? bf16rne(w1[k * 16 + n]) : (unsigned short)0;
    } else if (i < 2560) {
        int j = i - 512, n = j >> 5, k = j & 31;
        w2a[j] = (k < 16) ? bf16rne(w2[k * 64 + n]) : (unsigned short)0;
    } else if (i < 4608) {
        int j = i - 2560, n = j >> 6, k = j & 63;
        w3a[j] = bf16rne(w3[k * 32 + n]);
    }
}

// ---------------------------------------------------------------------------
// Per-point squared norms
// ---------------------------------------------------------------------------
template<int C>
__global__ void norms16_kernel(const unsigned short* __restrict__ feat, float* __restrict__ out) {
    int gid = blockIdx.x * blockDim.x + threadIdx.x;
    if (gid < BSZ * NPT) {
        const unsigned short* p = feat + (size_t)gid * C;
        float s = 0.f;
#pragma unroll
        for (int c = 0; c < C; ++c) {
            union { unsigned int u; float f; } v; v.u = ((unsigned int)p[c]) << 16;
            s = fmaf(v.f, v.f, s);
        }
        out[gid] = s;
    }
}

template<int C>
__global__ void norms_kernel(const float* __restrict__ feat, float* __restrict__ out) {
    int gid = blockIdx.x * blockDim.x + threadIdx.x;
    if (gid < BSZ * NPT) {
        const float* p = feat + (size_t)gid * C;
        float s = 0.f;
#pragma unroll
        for (int c = 0; c < C; ++c) s = fmaf(p[c], p[c], s);
        out[gid] = s;
    }
}

// ---------------------------------------------------------------------------
// KNN C=3, fp32, j-split JS=4, dual top-16 lists (even/odd candidates) with
// DIRECT INIT from the first 32 candidates (R14: kills the 32 guaranteed
// sentinel-filling inserts per lane that R13's counters exposed).
// Lane = query; wave scans a quarter of the js range; cross-wave merge at
// end (2 barriers).
// ---------------------------------------------------------------------------
template<int JS>
__launch_bounds__(256, 3)
__global__ void knn3_kernel(const float* __restrict__ feat,
                            const float* __restrict__ norms,
                            float* __restrict__ cand) {
    constexpr int JL = NPT / JS;
    constexpr int JP = JL / 4;
    const int b = blockIdx.z, js = blockIdx.y, i0 = blockIdx.x * 64;
    const int t = threadIdx.x, w = t >> 6, lane = t & 63;
    const float* fb = feat + (size_t)b * NPT * 3;
    const float* nb = norms + (size_t)b * NPT;

    __shared__ float sS[4][64][17];

    float q0, q1, q2;
    { const float* qp = fb + (size_t)(i0 + lane) * 3; q0 = qp[0]; q1 = qp[1]; q2 = qp[2]; }

    float LA[16], LB[16];
    const int jbeg = js * JL + w * JP;
    // direct init: candidates jbeg..jbeg+31 (even -> LA, odd -> LB)
#pragma unroll
    for (int jj = 0; jj < 32; jj += 2) {
        const int j = jbeg + jj;
        const float* pp = fb + (size_t)j * 3;
        LA[jj >> 1] = packkey(fmaf(-2.f, fmaf(q0, pp[0], fmaf(q1, pp[1], q2 * pp[2])), nb[j]), j);
        LB[jj >> 1] = packkey(fmaf(-2.f, fmaf(q0, pp[3], fmaf(q1, pp[4], q2 * pp[5])), nb[j + 1]), j + 1);
    }
    float mxA = max16(LA), mxB = max16(LB);

    auto insA = [&](float k) {
        if (k < mxA) {
#pragma unroll
            for (int u = 0; u < 16; ++u) LA[u] = (LA[u] == mxA) ? k : LA[u];
            mxA = max16(LA);
        }
    };
    auto insB = [&](float k) {
        if (k < mxB) {
#pragma unroll
            for (int u = 0; u < 16; ++u) LB[u] = (LB[u] == mxB) ? k : LB[u];
            mxB = max16(LB);
        }
    };

#pragma unroll 2
    for (int jj = 32; jj < JP; jj += 2) {
        const int j = jbeg + jj;
        const float* pp = fb + (size_t)j * 3;
        const float dA = fmaf(-2.f, fmaf(q0, pp[0], fmaf(q1, pp[1], q2 * pp[2])), nb[j]);
        const float dB = fmaf(-2.f, fmaf(q0, pp[3], fmaf(q1, pp[4], q2 * pp[5])), nb[j + 1]);
        insA(packkey(dA, j));
        insB(packkey(dB, j + 1));
    }
    // merge B into A
#pragma unroll
    for (int c = 0; c < 16; ++c) insA(LB[c]);

    // cross-wave merge (rows = lanes)
#pragma unroll
    for (int c = 0; c < 16; ++c) sS[w][lane][c] = LA[c];
    __syncthreads();
    if (w == 0 || w == 2) {
#pragma unroll
        for (int c = 0; c < 16; ++c) insA(sS[w + 1][lane][c]);
        if (w == 2) {
#pragma unroll
            for (int c = 0; c < 16; ++c) sS[2][lane][c] = LA[c];
        }
    }
    __syncthreads();
    if (w == 0) {
#pragma unroll
        for (int c = 0; c < 16; ++c) insA(sS[2][lane][c]);
        float* o = cand + (((size_t)b * NPT + i0 + lane) * JS + js) * 16;
#pragma unroll
        for (int c = 0; c < 16; ++c) o[c] = LA[c];
    }
}

// ---------------------------------------------------------------------------
// KNN via bf16 MFMA — exact R10 structure (single top-16 list, first-tile
// direct init, JS=4; measured 64 us — best of all variants tried R10-R13).
// A = 64 query rows stationary in registers; wave w streams its own 16
// candidates per 64-tile; scores via wave-private LDS strip (no barrier);
// cross-wave merge at end (2 barriers total).
// ---------------------------------------------------------------------------
template<int C, int JS>
__launch_bounds__(256, 3)
__global__ void knn_mfma_kernel(const unsigned short* __restrict__ fb16,
                                const float* __restrict__ norms,
                                float* __restrict__ cand) {
    constexpr int JL = NPT / JS;
    constexpr int KS = C / 32;
    const int b    = blockIdx.z;
    const int js   = blockIdx.y;
    const int i0   = blockIdx.x * 64;
    const int t    = threadIdx.x;
    const int w    = t >> 6;
    const int lane = t & 63;
    const int l15  = lane & 15;
    const int quad = lane >> 4;
    const unsigned short* fbb = fb16 + (size_t)b * NPT * C;
    const float* nb = norms + (size_t)b * NPT;

    __shared__ float sS[4][64][17];

    bf16x8 afr[KS * 4];
#pragma unroll
    for (int ks = 0; ks < KS; ++ks)
#pragma unroll
        for (int mi = 0; mi < 4; ++mi)
            afr[ks * 4 + mi] = *(const bf16x8*)(fbb + (size_t)(i0 + mi * 16 + l15) * C + ks * 32 + quad * 8);

    float L[16];
#pragma unroll
    for (int u = 0; u < 16; ++u) L[u] = 3e38f;
    float mx = 3e38f;

    auto ins = [&](float k) {
        if (k < mx) {
#pragma unroll
            for (int u = 0; u < 16; ++u) L[u] = (L[u] == mx) ? k : L[u];
            mx = max16(L);
        }
    };

    const int jbeg = js * JL;
#pragma unroll 1
    for (int j0 = jbeg; j0 < jbeg + JL; j0 += 64) {
        f32x4 acc[4];
#pragma unroll
        for (int mi = 0; mi < 4; ++mi) acc[mi] = (f32x4){0.f, 0.f, 0.f, 0.f};
        const unsigned short* prow = fbb + (size_t)(j0 + w * 16 + l15) * C + quad * 8;
#pragma unroll
        for (int ks = 0; ks < KS; ++ks) {
            const bf16x8 bfr = *(const bf16x8*)(prow + ks * 32);
#pragma unroll
            for (int mi = 0; mi < 4; ++mi)
                acc[mi] = __builtin_amdgcn_mfma_f32_16x16x32_bf16(afr[ks * 4 + mi], bfr, acc[mi], 0, 0, 0);
        }
        const float nv  = nb[j0 + w * 16 + l15];
        const int  cidx = j0 + w * 16 + l15;
        // D layout: col(candidate)=l15, row(query)=mi*16+quad*4+r. Write
        // packed keys to this wave's private strip; read back transposed.
#pragma unroll
        for (int mi = 0; mi < 4; ++mi)
#pragma unroll
            for (int r = 0; r < 4; ++r)
                sS[w][mi * 16 + quad * 4 + r][l15] = packkey(fmaf(-2.f, acc[mi][r], nv), cidx);
        float k0[16];
#pragma unroll
        for (int c = 0; c < 16; ++c) k0[c] = sS[w][lane][c];
        if (j0 == jbeg) {
#pragma unroll
            for (int c = 0; c < 16; ++c) L[c] = k0[c];
            mx = max16(L);
        } else {
#pragma unroll
            for (int c = 0; c < 16; ++c) ins(k0[c]);
        }
    }

    // cross-wave merge: per query row, 4 column-partition lists -> 16
#pragma unroll
    for (int c = 0; c < 16; ++c) sS[w][lane][c] = L[c];
    __syncthreads();
    if (w == 0 || w == 2) {
#pragma unroll
        for (int c = 0; c < 16; ++c) ins(sS[w + 1][lane][c]);
        if (w == 2) {
#pragma unroll
            for (int c = 0; c < 16; ++c) sS[2][lane][c] = L[c];
        }
    }
    __syncthreads();
    if (w == 0) {
#pragma unroll
        for (int c = 0; c < 16; ++c) ins(sS[2][lane][c]);
        float* o = cand + (((size_t)b * NPT + i0 + lane) * JS + js) * 16;
#pragma unroll
        for (int c = 0; c < 16; ++c) o[c] = L[c];
    }
}

// ---------------------------------------------------------------------------
// Merge JS packed-key lists per query -> final top-16 indices.
// ---------------------------------------------------------------------------
template<int JS>
__launch_bounds__(256)
__global__ void knn_merge_kernel(const float* __restrict__ cand, int* __restrict__ knn_out) {
    const int q = blockIdx.x * 256 + threadIdx.x;
    const float* pd = cand + (size_t)q * JS * 16;
    float L[16];
#pragma unroll
    for (int u = 0; u < 16; ++u) L[u] = pd[u];
    float mx = max16(L);
#pragma unroll 2
    for (int u = 16; u < JS * 16; ++u) {
        const float k = pd[u];
        if (k < mx) {
#pragma unroll
            for (int v = 0; v < 16; ++v) L[v] = (L[v] == mx) ? k : L[v];
            mx = max16(L);
        }
    }
    int* o = knn_out + (size_t)q * KNB;
#pragma unroll
    for (int u = 0; u < 16; ++u) {
        union { float f; unsigned int v; } z; z.f = L[u];
        o[u] = (int)(z.v & 2047u);
    }
}

// ---------------------------------------------------------------------------
// Block 1 via MFMA, swapped operands (R10, unchanged). Writes x2 in bf16.
// ---------------------------------------------------------------------------
__launch_bounds__(256, 3)
__global__ void block1_mfma_kernel(const float* __restrict__ x, const int* __restrict__ knn,
                                   const unsigned short* __restrict__ w1a, const float* __restrict__ b1,
                                   const unsigned short* __restrict__ w2a, const float* __restrict__ b2,
                                   const unsigned short* __restrict__ w3a, const float* __restrict__ b3,
                                   unsigned short* __restrict__ x2b) {
    const int w = threadIdx.x >> 6, lane = threadIdx.x & 63;
    const int l15 = lane & 15, quad = lane >> 4;

    const bf16x8 W1 = *(const bf16x8*)(w1a + l15 * 32 + quad * 8);
    bf16x8 W2[4];
#pragma unroll
    for (int nt = 0; nt < 4; ++nt)
        W2[nt] = *(const bf16x8*)(w2a + (nt * 16 + l15) * 32 + quad * 8);
    bf16x8 W3[2][2];
#pragma unroll
    for (int tt = 0; tt < 2; ++tt)
#pragma unroll
        for (int ks = 0; ks < 2; ++ks)
            W3[tt][ks] = *(const bf16x8*)(w3a + (tt * 16 + l15) * 64 + ks * 32 + quad * 8);
    float b1v[4], b2v[4][4], b3v[2][4];
#pragma unroll
    for (int r = 0; r < 4; ++r) b1v[r] = b1[quad * 4 + r];
#pragma unroll
    for (int nt = 0; nt < 4; ++nt)
#pragma unroll
        for (int r = 0; r < 4; ++r) b2v[nt][r] = b2[nt * 16 + quad * 4 + r];
#pragma unroll
    for (int tt = 0; tt < 2; ++tt)
#pragma unroll
        for (int r = 0; r < 4; ++r) b3v[tt][r] = b3[tt * 16 + quad * 4 + r];

    const int src0 = ((2 * quad) & 3) * 16 + l15;
    const int src1 = ((2 * quad + 1) & 3) * 16 + l15;
    const int ntsel = quad >> 1;

    const int p0 = blockIdx.x * 16 + w * 4;
#pragma unroll 1
    for (int pi = 0; pi < 4; ++pi) {
        const int p = p0 + pi, b = p >> 11, n = p & (NPT - 1);
        int d0 = 0, d1 = 0, d2 = 0;
        if (quad == 0) {
            const float* xc = x + ((size_t)b * NPT + n) * 3;
            const int jn = knn[(size_t)p * KNB + l15];
            const float* xn = x + ((size_t)b * NPT + jn) * 3;
            const unsigned s0 = bf16rne(xc[0]), s1 = bf16rne(xc[1]), s2 = bf16rne(xc[2]);
            const unsigned s3 = bf16rne(xn[0]), s4 = bf16rne(xn[1]), s5 = bf16rne(xn[2]);
            d0 = (int)(s0 | (s1 << 16));
            d1 = (int)(s2 | (s3 << 16));
            d2 = (int)(s4 | (s5 << 16));
        }
        union { int i[4]; bf16x8 v; } B1;
        B1.i[0] = d0; B1.i[1] = d1; B1.i[2] = d2; B1.i[3] = 0;
        const f32x4 a1 = __builtin_amdgcn_mfma_f32_16x16x32_bf16(W1, B1.v, (f32x4){0.f, 0.f, 0.f, 0.f}, 0, 0, 0);

        int h10, h11;
        {
            const unsigned t0 = bf16rne(lrelu(a1[0] + b1v[0]));
            const unsigned t1 = bf16rne(lrelu(a1[1] + b1v[1]));
            const unsigned t2 = bf16rne(lrelu(a1[2] + b1v[2]));
            const unsigned t3 = bf16rne(lrelu(a1[3] + b1v[3]));
            h10 = (int)(t0 | (t1 << 16));
            h11 = (int)(t2 | (t3 << 16));
        }
        union { int i[4]; bf16x8 v; } B2;
        {
            const int e0 = __shfl(h10, src0), e1 = __shfl(h11, src0);
            const int e2 = __shfl(h10, src1), e3 = __shfl(h11, src1);
            const bool val = quad < 2;
            B2.i[0] = val ? e0 : 0; B2.i[1] = val ? e1 : 0;
            B2.i[2] = val ? e2 : 0; B2.i[3] = val ? e3 : 0;
        }
        f32x4 a2[4];
#pragma unroll
        for (int nt = 0; nt < 4; ++nt)
            a2[nt] = __builtin_amdgcn_mfma_f32_16x16x32_bf16(W2[nt], B2.v, (f32x4){0.f, 0.f, 0.f, 0.f}, 0, 0, 0);
        int dpk[4][2];
#pragma unroll
        for (int nt = 0; nt < 4; ++nt) {
            const unsigned t0 = bf16rne(lrelu(a2[nt][0] + b2v[nt][0]));
            const unsigned t1 = bf16rne(lrelu(a2[nt][1] + b2v[nt][1]));
            const unsigned t2 = bf16rne(lrelu(a2[nt][2] + b2v[nt][2]));
            const unsigned t3 = bf16rne(lrelu(a2[nt][3] + b2v[nt][3]));
            dpk[nt][0] = (int)(t0 | (t1 << 16));
            dpk[nt][1] = (int)(t2 | (t3 << 16));
        }
        f32x4 a3[2] = { (f32x4){0.f, 0.f, 0.f, 0.f}, (f32x4){0.f, 0.f, 0.f, 0.f} };
#pragma unroll
        for (int ks = 0; ks < 2; ++ks) {
            union { int i[4]; bf16x8 v; } B3;
            const int a0l = __shfl(dpk[2 * ks][0], src0), a0h = __shfl(dpk[2 * ks + 1][0], src0);
            const int a1l = __shfl(dpk[2 * ks][1], src0), a1h = __shfl(dpk[2 * ks + 1][1], src0);
            const int a2l = __shfl(dpk[2 * ks][0], src1), a2h = __shfl(dpk[2 * ks + 1][0], src1);
            const int a3l = __shfl(dpk[2 * ks][1], src1), a3h = __shfl(dpk[2 * ks + 1][1], src1);
            B3.i[0] = ntsel ? a0h : a0l;
            B3.i[1] = ntsel ? a1h : a1l;
            B3.i[2] = ntsel ? a2h : a2l;
            B3.i[3] = ntsel ? a3h : a3l;
#pragma unroll
            for (int tt = 0; tt < 2; ++tt)
                a3[tt] = __builtin_amdgcn_mfma_f32_16x16x32_bf16(W3[tt][ks], B3.v, a3[tt], 0, 0, 0);
        }
#pragma unroll
        for (int tt = 0; tt < 2; ++tt) {
#pragma unroll
            for (int r = 0; r < 4; ++r) {
                float s = lrelu(a3[tt][r] + b3v[tt][r]);
                s += __shfl_xor(s, 1);
                s += __shfl_xor(s, 2);
                s += __shfl_xor(s, 4);
                s += __shfl_xor(s, 8);
                if (l15 == 0)
                    x2b[(size_t)p * 32 + tt * 16 + quad * 4 + r] = bf16rne(s);
            }
        }
    }
}

// ---------------------------------------------------------------------------
// Block 2 fused, weight-stationary (R9/R10, unchanged). x3 out bf16.
// ---------------------------------------------------------------------------
__launch_bounds__(256, 2)
__global__ void block2_fused_kernel(const unsigned short* __restrict__ x2b,
                                    const int* __restrict__ knn,
                                    const unsigned short* __restrict__ w1t,  // [256][64]
                                    const float* __restrict__ b1,
                                    const unsigned short* __restrict__ w2t,  // [128][256]
                                    const float* __restrict__ b2,
                                    unsigned short* __restrict__ x3b) {
    const int w    = threadIdx.x >> 6;
    const int lane = threadIdx.x & 63;
    const int l15  = lane & 15, quad = lane >> 4;
    __shared__ __align__(16) unsigned short sH1[2][16][264];

    bf16x8 B1[4][2];
#pragma unroll
    for (int nt2 = 0; nt2 < 4; ++nt2)
#pragma unroll
        for (int ks = 0; ks < 2; ++ks)
            B1[nt2][ks] = *(const bf16x8*)(w1t + (size_t)(w * 64 + nt2 * 16 + l15) * 64 + ks * 32 + quad * 8);
    bf16x8 B2[2][8];
#pragma unroll
    for (int nt2 = 0; nt2 < 2; ++nt2)
#pragma unroll
        for (int ks = 0; ks < 8; ++ks)
            B2[nt2][ks] = *(const bf16x8*)(w2t + (size_t)(w * 32 + nt2 * 16 + l15) * 256 + ks * 32 + quad * 8);
    float b1v[4];
#pragma unroll
    for (int nt2 = 0; nt2 < 4; ++nt2) b1v[nt2] = b1[w * 64 + nt2 * 16 + l15];
    float b2v[2];
#pragma unroll
    for (int nt2 = 0; nt2 < 2; ++nt2) b2v[nt2] = b2[w * 32 + nt2 * 16 + l15];

    const int p0 = blockIdx.x * 8;
#pragma unroll 1
    for (int pi = 0; pi < 8; ++pi) {
        const int p = p0 + pi, b = p >> 11, buf = pi & 1;
        const int nbr = knn[(size_t)p * KNB + l15];
        const bf16x8 a0 = *(const bf16x8*)(x2b + (size_t)p * 32 + quad * 8);
        const bf16x8 a1 = *(const bf16x8*)(x2b + ((size_t)(b * NPT) + nbr) * 32 + quad * 8);
#pragma unroll
        for (int nt2 = 0; nt2 < 4; ++nt2) {
            f32x4 acc = (f32x4){0.f, 0.f, 0.f, 0.f};
            acc = __builtin_amdgcn_mfma_f32_16x16x32_bf16(a0, B1[nt2][0], acc, 0, 0, 0);
            acc = __builtin_amdgcn_mfma_f32_16x16x32_bf16(a1, B1[nt2][1], acc, 0, 0, 0);
#pragma unroll
            for (int r = 0; r < 4; ++r)
                sH1[buf][quad * 4 + r][w * 64 + nt2 * 16 + l15] = bf16rne(lrelu(acc[r] + b1v[nt2]));
        }
        __syncthreads();
        bf16x8 af[8];
#pragma unroll
        for (int ks = 0; ks < 8; ++ks)
            af[ks] = *(const bf16x8*)&sH1[buf][l15][ks * 32 + quad * 8];
#pragma unroll
        for (int nt2 = 0; nt2 < 2; ++nt2) {
            f32x4 acc = (f32x4){0.f, 0.f, 0.f, 0.f};
#pragma unroll
            for (int ks = 0; ks < 8; ++ks)
                acc = __builtin_amdgcn_mfma_f32_16x16x32_bf16(af[ks], B2[nt2][ks], acc, 0, 0, 0);
            float s = 0.f;
#pragma unroll
            for (int r = 0; r < 4; ++r) s += lrelu(acc[r] + b2v[nt2]);
            s += __shfl_xor(s, 16);
            s += __shfl_xor(s, 32);
            if (quad == 0) x3b[(size_t)p * 128 + w * 32 + nt2 * 16 + l15] = bf16rne(s);
        }
    }
}

// ---------------------------------------------------------------------------
// Block 3 fused, weight-stationary (R9, unchanged): x4 fp32 out.
// ---------------------------------------------------------------------------
__launch_bounds__(256, 3)
__global__ void block3_fused_kernel(const unsigned short* __restrict__ x3b,
                                    const int* __restrict__ knn,
                                    const unsigned short* __restrict__ w3t,  // [128][256]
                                    const float* __restrict__ bias,
                                    float* __restrict__ x4) {
    const int w    = threadIdx.x >> 6;
    const int lane = threadIdx.x & 63;
    const int l15  = lane & 15, quad = lane >> 4;

    bf16x8 B3[2][8];
#pragma unroll
    for (int nt2 = 0; nt2 < 2; ++nt2)
#pragma unroll
        for (int ks = 0; ks < 8; ++ks)
            B3[nt2][ks] = *(const bf16x8*)(w3t + (size_t)(w * 32 + nt2 * 16 + l15) * 256 + ks * 32 + quad * 8);
    float bv[2];
#pragma unroll
    for (int nt2 = 0; nt2 < 2; ++nt2) bv[nt2] = bias[w * 32 + nt2 * 16 + l15];

    const int p0 = blockIdx.x * 8;
#pragma unroll 1
    for (int pi = 0; pi < 8; ++pi) {
        const int p = p0 + pi, b = p >> 11;
        const int nbr = knn[(size_t)p * KNB + l15];
        const unsigned short* ctr = x3b + (size_t)p * 128 + quad * 8;
        const unsigned short* nbp = x3b + ((size_t)(b * NPT) + nbr) * 128 + quad * 8;
        bf16x8 af[8];
#pragma unroll
        for (int ks = 0; ks < 4; ++ks) af[ks] = *(const bf16x8*)(ctr + ks * 32);
#pragma unroll
        for (int ks = 0; ks < 4; ++ks) af[4 + ks] = *(const bf16x8*)(nbp + ks * 32);
#pragma unroll
        for (int nt2 = 0; nt2 < 2; ++nt2) {
            f32x4 acc = (f32x4){0.f, 0.f, 0.f, 0.f};
#pragma unroll
            for (int ks = 0; ks < 8; ++ks)
                acc = __builtin_amdgcn_mfma_f32_16x16x32_bf16(af[ks], B3[nt2][ks], acc, 0, 0, 0);
            float s = 0.f;
#pragma unroll
            for (int r = 0; r < 4; ++r) s += lrelu(acc[r] + bv[nt2]);
            s += __shfl_xor(s, 16);
            s += __shfl_xor(s, 32);
            if (quad == 0) x4[(size_t)p * 128 + w * 32 + nt2 * 16 + l15] = s;
        }
    }
}

// ---------------------------------------------------------------------------
// Maxpool stage 1
// ---------------------------------------------------------------------------
__launch_bounds__(128)
__global__ void maxpool_partial_kernel(const float* __restrict__ x4,
                                       float* __restrict__ part) {
    const int chunk = blockIdx.x, b = blockIdx.y, t = threadIdx.x;
    const float* xb = x4 + ((size_t)b * NPT + (size_t)chunk * 128) * 128;
    float m = -1e30f;
#pragma unroll 8
    for (int n = 0; n < 128; ++n) m = fmaxf(m, xb[(size_t)n * 128 + t]);
    part[((size_t)b * 16 + chunk) * 128 + t] = m;
}

// ---------------------------------------------------------------------------
// Head stage 2
// ---------------------------------------------------------------------------
__launch_bounds__(128)
__global__ void head2_kernel(const float* __restrict__ part,
                             const float* __restrict__ fc1w, const float* __restrict__ fc1b,
                             const float* __restrict__ fc2w, const float* __restrict__ fc2b,
                             const float* __restrict__ fc3w, const float* __restrict__ fc3b,
                             float* __restrict__ out) {
    const int g = blockIdx.x, b = blockIdx.y, t = threadIdx.x;
    __shared__ float s5[128], s6[128], s7[128];
    float m = -1e30f;
#pragma unroll
    for (int c = 0; c < 16; ++c)
        m = fmaxf(m, part[((size_t)b * 16 + c) * 128 + t]);
    s5[t] = m;
    __syncthreads();
    float a = fc1b[t];
#pragma unroll 4
    for (int i = 0; i < 128; ++i) a = fmaf(s5[i], fc1w[i * 128 + t], a);
    s6[t] = lrelu(a);
    __syncthreads();
    a = fc2b[t];
#pragma unroll 4
    for (int i = 0; i < 128; ++i) a = fmaf(s6[i], fc2w[i * 128 + t], a);
    s7[t] = lrelu(a);
    __syncthreads();
    const int o = g * 128 + t;
    float acc = fc3b[o];
#pragma unroll 4
    for (int i = 0; i < 128; ++i) acc = fmaf(s7[i], fc3w[(size_t)i * 6144 + o], acc);
    out[(size_t)b * 6144 + o] = acc;
}

// ---------------------------------------------------------------------------
extern "C" void kernel_launch(void* const* d_in, const int* in_sizes, int n_in,
                              void* d_out, int out_size, void* d_ws, size_t ws_size,
                              hipStream_t stream) {
    const float* x    = (const float*)d_in[0];
    const float* h1w1 = (const float*)d_in[1];
    const float* h1b1 = (const float*)d_in[2];
    const float* h1w2 = (const float*)d_in[3];
    const float* h1b2 = (const float*)d_in[4];
    const float* h1w3 = (const float*)d_in[5];
    const float* h1b3 = (const float*)d_in[6];
    const float* h2w1 = (const float*)d_in[7];
    const float* h2b1 = (const float*)d_in[8];
    const float* h2w2 = (const float*)d_in[9];
    const float* h2b2 = (const float*)d_in[10];
    const float* h3w1 = (const float*)d_in[11];
    const float* h3b1 = (const float*)d_in[12];
    const float* fc1w = (const float*)d_in[13];
    const float* fc1b = (const float*)d_in[14];
    const float* fc2w = (const float*)d_in[15];
    const float* fc2b = (const float*)d_in[16];
    const float* fc3w = (const float*)d_in[17];
    const float* fc3b = (const float*)d_in[18];

    float* ws = (float*)d_ws;
    unsigned short* x2b16 = (unsigned short*)ws;              //  524288 sh (262144 fl)
    unsigned short* x3b16 = (unsigned short*)(ws + 262144);   // 2097152 sh (1048576 fl)
    float* x4   = ws + 1310720;                               // 2097152 fl
    int*   idx  = (int*)(ws + 3407872);                       //  262144 int
    float* nrm  = ws + 3670016;                               //   16384 fl
    float* part = ws + 3686400;                               //   16384 fl
    unsigned short* w1t = (unsigned short*)(ws + 3702784);    //  16384 sh
    unsigned short* w2t = (unsigned short*)(ws + 3710976);    //  32768 sh
    unsigned short* w3t = (unsigned short*)(ws + 3727360);    //  32768 sh
    unsigned short* w1a = (unsigned short*)(ws + 3743744);    //    512 sh
    unsigned short* w2a = (unsigned short*)(ws + 3744000);    //   2048 sh
    unsigned short* w3a = (unsigned short*)(ws + 3745024);    //   2048 sh
    float* cd   = ws + 3746048;                               // 1048576 fl (~19.2 MB total)
    float* out  = (float*)d_out;

    const dim3 kg(32, 4, 8);   // (qtile, j-split=4, batch)

    wprep_kernel<<<64, 256, 0, stream>>>(h2w1, w1t, 64, 256);
    wprep_kernel<<<128, 256, 0, stream>>>(h2w2, w2t, 256, 128);
    wprep_kernel<<<128, 256, 0, stream>>>(h3w1, w3t, 256, 128);
    wprep_b1_kernel<<<18, 256, 0, stream>>>(h1w1, h1w2, h1w3, w1a, w2a, w3a);

    norms_kernel<3><<<64, 256, 0, stream>>>(x, nrm);
    knn3_kernel<4><<<kg, 256, 0, stream>>>(x, nrm, cd);
    knn_merge_kernel<4><<<64, 256, 0, stream>>>(cd, idx);
    block1_mfma_kernel<<<1024, 256, 0, stream>>>(x, idx, w1a, h1b1, w2a, h1b2, w3a, h1b3, x2b16);

    norms16_kernel<32><<<64, 256, 0, stream>>>(x2b16, nrm);
    knn_mfma_kernel<32, 4><<<kg, 256, 0, stream>>>(x2b16, nrm, cd);
    knn_merge_kernel<4><<<64, 256, 0, stream>>>(cd, idx);
    block2_fused_kernel<<<BSZ * NPT / 8, 256, 0, stream>>>(x2b16, idx, w1t, h2b1, w2t, h2b2, x3b16);

    norms16_kernel<128><<<64, 256, 0, stream>>>(x3b16, nrm);
    knn_mfma_kernel<128, 4><<<kg, 256, 0, stream>>>(x3b16, nrm, cd);
    knn_merge_kernel<4><<<64, 256, 0, stream>>>(cd, idx);
    block3_fused_kernel<<<BSZ * NPT / 8, 256, 0, stream>>>(x3b16, idx, w3t, h3b1, x4);

    maxpool_partial_kernel<<<dim3(16, 8), 128, 0, stream>>>(x4, part);
    head2_kernel<<<dim3(48, 8), 128, 0, stream>>>(part, fc1w, fc1b, fc2w, fc2b,
                                                  fc3w, fc3b, out);
}